// Round 3
// baseline (1105.574 us; speedup 1.0000x reference)
//
#include <hip/hip_runtime.h>
#include <stdint.h>

// Problem: B=8 H=16 S=512 D=64; BH=128 heads; V has 3 "v" planes per head.
// out[bh][v][q][d] = sum_k attn[bh][q][k] * t2[bh][v][k][d]
// attn = dropout(softmax(Q K^T * t3), p=0.35, jax key(42))
//
// Dropout mask reproduces jax.random.bernoulli(key(42), 0.65, [8,16,1,512,512])
// under jax_threefry_partitionable (default in modern JAX):
//   per element flat-index e (uint64): block = (hi32(e), lo32(e)) = (0, e),
//   (o1, o2) = threefry2x32(key=(0,42), block);
//   bits = o1 ^ o2   // <= 32-bit path: convert_element_type(bits1 ^ bits2)
//   u = bitcast((bits>>9)|0x3f800000) - 1.0f; keep = u < 0.65f.

#define S_LEN 512
#define D_HEAD 64
#define NCH 8          // 512 / 64 k-chunks
#define QPB 4          // q rows per block (1 per wave)

__device__ __forceinline__ uint32_t rotl32(uint32_t x, int r) {
    return (x << r) | (x >> (32 - r));
}

// Threefry-2x32, 20 rounds, key = (0, 42)  [jax.random.key(42) -> (0,42)]
__device__ __forceinline__ uint2 threefry_0_42(uint32_t x0, uint32_t x1) {
    const uint32_t ks0 = 0u, ks1 = 42u, ks2 = 0u ^ 42u ^ 0x1BD11BDAu;
    x0 += ks0; x1 += ks1;
#define TFR(r) { x0 += x1; x1 = rotl32(x1, r); x1 ^= x0; }
    TFR(13) TFR(15) TFR(26) TFR(6)
    x0 += ks1; x1 += ks2 + 1u;
    TFR(17) TFR(29) TFR(16) TFR(24)
    x0 += ks2; x1 += ks0 + 2u;
    TFR(13) TFR(15) TFR(26) TFR(6)
    x0 += ks0; x1 += ks1 + 3u;
    TFR(17) TFR(29) TFR(16) TFR(24)
    x0 += ks1; x1 += ks2 + 4u;
    TFR(13) TFR(15) TFR(26) TFR(6)
    x0 += ks2; x1 += ks0 + 5u;
#undef TFR
    return make_uint2(x0, x1);
}

__global__ __launch_bounds__(256) void attn_dropout_kernel(
    const float* __restrict__ t0,   // Q  [128][512][64]
    const float* __restrict__ t1,   // K  [128][512][64]
    const float* __restrict__ t2,   // V  [128][3][512][64]
    const float* __restrict__ t3,   // scalar scale
    float* __restrict__ out)        // [128][3][512][64]
{
    __shared__ float Kl[64][65];          // K chunk, +1 pad (2-way conflict = free)
    __shared__ float Ql[QPB][D_HEAD];     // Q rows for this block
    __shared__ float Al[QPB][S_LEN];      // masked, fully-scaled attn rows

    const int bh   = blockIdx.x;          // 0..127
    const int qb   = blockIdx.y;          // 0..127
    const int tid  = threadIdx.x;
    const int wave = tid >> 6;
    const int lane = tid & 63;
    const float scale = t3[0];

    const int q = qb * QPB + wave;

    // ---- stage Q rows (256 threads load 4x64 floats, coalesced) ----
    Ql[tid >> 6][tid & 63] = t0[(size_t)bh * 32768 + (size_t)(qb * QPB + (tid >> 6)) * 64 + (tid & 63)];

    const float* Kbase = t1 + (size_t)bh * 32768;

    float s[NCH];
    for (int c = 0; c < NCH; ++c) {
        __syncthreads();
        // ---- stage K chunk: rows c*64 .. c*64+63, coalesced float4 ----
        {
            const int r = tid >> 2;
            const int seg = (tid & 3) * 16;
            const float4* src = reinterpret_cast<const float4*>(Kbase + (size_t)(c * 64 + r) * 64 + seg);
            float4 a0 = src[0], a1 = src[1], a2 = src[2], a3 = src[3];
            float* dst = &Kl[r][seg];
            dst[0]=a0.x; dst[1]=a0.y; dst[2]=a0.z; dst[3]=a0.w;
            dst[4]=a1.x; dst[5]=a1.y; dst[6]=a1.z; dst[7]=a1.w;
            dst[8]=a2.x; dst[9]=a2.y; dst[10]=a2.z; dst[11]=a2.w;
            dst[12]=a3.x; dst[13]=a3.y; dst[14]=a3.z; dst[15]=a3.w;
        }
        __syncthreads();
        // ---- scores: lane computes score for k = c*64 + lane ----
        float acc = 0.f;
#pragma unroll
        for (int d = 0; d < D_HEAD; ++d) {
            acc += Ql[wave][d] * Kl[lane][d];   // Ql: LDS broadcast; Kl: 2-way (free)
        }
        s[c] = acc * scale;
    }

    // ---- softmax over the row (held as s[c], k = c*64+lane) ----
    float m = s[0];
#pragma unroll
    for (int c = 1; c < NCH; ++c) m = fmaxf(m, s[c]);
#pragma unroll
    for (int off = 32; off; off >>= 1) m = fmaxf(m, __shfl_xor(m, off));

    float p[NCH];
    float den = 0.f;
#pragma unroll
    for (int c = 0; c < NCH; ++c) { p[c] = __expf(s[c] - m); den += p[c]; }
#pragma unroll
    for (int off = 32; off; off >>= 1) den += __shfl_xor(den, off);

    const float inv = 1.0f / (den * 0.65f);   // fold softmax denom + 1/(1-p) into attn

    // ---- dropout mask (JAX partitionable threefry) + park scaled attn in LDS ----
    // flat index e = (bh*512+q)*512 + k ; block=(0,e), bits = o1 ^ o2
    const uint32_t ebase = ((uint32_t)bh * 512u + (uint32_t)q) * 512u;
#pragma unroll
    for (int c = 0; c < NCH; ++c) {
        const uint32_t e = ebase + (uint32_t)(c * 64 + lane);
        uint2 r = threefry_0_42(0u, e);
        const uint32_t bits = r.x ^ r.y;
        const float u = __uint_as_float((bits >> 9) | 0x3F800000u) - 1.0f;
        Al[wave][c * 64 + lane] = (u < 0.65f) ? p[c] * inv : 0.0f;
    }

    // ---- PV: out[v][q][d=lane] = sum_k Al[k] * V[v][k][d] ----
    float o0 = 0.f, o1 = 0.f, o2 = 0.f;
    const float* Vb = t2 + (size_t)bh * 98304;   // [3][512][64]
#pragma unroll 8
    for (int k = 0; k < S_LEN; ++k) {
        const float a = Al[wave][k];             // uniform LDS read -> broadcast
        const size_t kk = (size_t)k * 64 + lane;
        o0 += a * Vb[kk];
        o1 += a * Vb[32768 + kk];
        o2 += a * Vb[65536 + kk];
    }

    const size_t ob = (size_t)bh * 98304 + (size_t)q * 64 + lane;
    out[ob]         = o0;
    out[ob + 32768] = o1;
    out[ob + 65536] = o2;
}

extern "C" void kernel_launch(void* const* d_in, const int* in_sizes, int n_in,
                              void* d_out, int out_size, void* d_ws, size_t ws_size,
                              hipStream_t stream) {
    const float* t0 = (const float*)d_in[0];
    const float* t1 = (const float*)d_in[1];
    const float* t2 = (const float*)d_in[2];
    const float* t3 = (const float*)d_in[3];
    float* out = (float*)d_out;

    dim3 grid(128, 128);   // (bh, q-block of 4 rows)
    dim3 block(256);
    attn_dropout_kernel<<<grid, block, 0, stream>>>(t0, t1, t2, t3, out);
}

// Round 5
// 247.812 us; speedup vs baseline: 4.4613x; 4.4613x over previous
//
#include <hip/hip_runtime.h>
#include <stdint.h>

// B=8 H=16 S=512 D=64; BH=128 heads; V/out have 3 planes per head.
// out[bh][v][q][d] = sum_k dropout(softmax(QK^T*t3))[q][k] * V[bh][v][k][d]
// Dropout: jax.random.bernoulli(key(42), 0.65) partitionable threefry:
//   (o1,o2)=threefry2x32((0,42),(0,e)); bits=o1^o2; u=bitcast((bits>>9)|0x3f800000)-1; keep=u<0.65
// Softmax WITHOUT max subtraction: |s|<=~50 so exp(s) is fp32-safe; identical result.
//
// Precision: QK^T uses split-bf16 (q=q_hi+q_lo, k=k_hi+k_lo; 3 MFMAs:
// hi*hi + lo*hi + hi*lo) => score error ~1e-3 (fp32-like). P,V stay bf16
// (~0.02 abs out error, threshold 0.1575).
//
// Layout: grid = 128 bh x 4 qtiles (bh fastest => same-head blocks share an
// XCD L2). Block 512 thr = 8 waves x 16 q-rows. Per 64-key chunk: stage
// K_hi/K_lo + V^T bf16 in LDS (XOR-swizzled), QK^T via 16x16x32 MFMA,
// exp+threefry+mask in regs, P->bf16 via per-wave LDS (C->A layout bridge),
// PV via MFMA, final scale by 1/(den*0.65).

typedef __attribute__((ext_vector_type(8))) short short8;
typedef __attribute__((ext_vector_type(4))) float f32x4;

__device__ __forceinline__ uint32_t rotl32(uint32_t x, int r) {
    return (x << r) | (x >> (32 - r));
}

// Threefry-2x32, 20 rounds, key=(0,42), block=(0,e); returns o1^o2.
__device__ __forceinline__ uint32_t threefry_bits(uint32_t e) {
    uint32_t x0 = 0u, x1 = e;
    const uint32_t ks0 = 0u, ks1 = 42u, ks2 = 0x1BD11BDAu ^ 42u;
    x0 += ks0; x1 += ks1;
#define TFR(r) { x0 += x1; x1 = rotl32(x1, r); x1 ^= x0; }
    TFR(13) TFR(15) TFR(26) TFR(6)
    x0 += ks1; x1 += ks2 + 1u;
    TFR(17) TFR(29) TFR(16) TFR(24)
    x0 += ks2; x1 += ks0 + 2u;
    TFR(13) TFR(15) TFR(26) TFR(6)
    x0 += ks0; x1 += ks1 + 3u;
    TFR(17) TFR(29) TFR(16) TFR(24)
    x0 += ks1; x1 += ks2 + 4u;
    TFR(13) TFR(15) TFR(26) TFR(6)
    x0 += ks2; x1 += ks0 + 5u;
#undef TFR
    return x0 ^ x1;
}

// fp32 -> bf16 round-to-nearest-even (bits in a short)
__device__ __forceinline__ short f2bf(float x) {
    uint32_t u = __float_as_uint(x);
    u += 0x7FFFu + ((u >> 16) & 1u);
    return (short)(u >> 16);
}
__device__ __forceinline__ float bf2f(short b) {
    return __uint_as_float(((uint32_t)(uint16_t)b) << 16);
}

__global__ __launch_bounds__(512, 2) void attn_mfma_kernel(
    const float* __restrict__ Q,   // [128][512][64]
    const float* __restrict__ K,   // [128][512][64]
    const float* __restrict__ V,   // [128][3][512][64]
    const float* __restrict__ t3,
    float* __restrict__ out)       // [128][3][512][64]
{
    // LDS: K_hi 8KB | K_lo 8KB | VT 3x8KB | P 8 waves x 2KB  = 56KB
    __shared__ char smem[57344];

    const int bh = blockIdx.x & 127;
    const int qt = blockIdx.x >> 7;          // 0..3
    const int tid = threadIdx.x;
    const int w   = tid >> 6;                // wave 0..7
    const int l   = tid & 63;
    const int lg  = l >> 4;                  // lane group 0..3
    const int lr  = l & 15;
    const float scale = t3[0];

    const float* Qb = Q + (size_t)bh * 32768;
    const float* Kb = K + (size_t)bh * 32768;
    const float* Vb = V + (size_t)bh * 98304;

    // ---- Q A-frags (hi+lo split): lane holds Q[qrow0 + lr][u*32 + lg*8 + j] ----
    short8 qhi[2], qlo[2];
    {
        const float* qp = Qb + (size_t)(qt * 128 + w * 16 + lr) * 64;
        #pragma unroll
        for (int u = 0; u < 2; ++u) {
            const float4* p4 = reinterpret_cast<const float4*>(qp + u * 32 + lg * 8);
            float4 a = p4[0], b = p4[1];
            float vals[8] = {a.x, a.y, a.z, a.w, b.x, b.y, b.z, b.w};
            short8 th, tl;
            #pragma unroll
            for (int j = 0; j < 8; ++j) {
                short h = f2bf(vals[j]);
                th[j] = h;
                tl[j] = f2bf(vals[j] - bf2f(h));
            }
            qhi[u] = th; qlo[u] = tl;
        }
    }

    f32x4 accO[3][4];
    #pragma unroll
    for (int v = 0; v < 3; ++v)
        #pragma unroll
        for (int nt = 0; nt < 4; ++nt)
            accO[v][nt] = (f32x4){0.f, 0.f, 0.f, 0.f};
    float lsum[4] = {0.f, 0.f, 0.f, 0.f};

    char* Pw = smem + 40960 + w * 2048;      // per-wave P tile [16 q][64 k] bf16

    for (int c = 0; c < 8; ++c) {
        const int k0 = c * 64;

        // ---- stage K chunk (hi+lo): K[key 0..63][d 0..63] bf16, swizzled ----
        {
            const int r  = tid >> 3;         // key row 0..63
            const int sg = tid & 7;          // 16B slot (8 bf16)
            const float4* p4 = reinterpret_cast<const float4*>(
                Kb + (size_t)(k0 + r) * 64 + sg * 8);
            float4 a = p4[0], b = p4[1];
            float vals[8] = {a.x, a.y, a.z, a.w, b.x, b.y, b.z, b.w};
            short8 th, tl;
            #pragma unroll
            for (int j = 0; j < 8; ++j) {
                short h = f2bf(vals[j]);
                th[j] = h;
                tl[j] = f2bf(vals[j] - bf2f(h));
            }
            const int off = r * 128 + ((sg * 16) ^ ((r & 7) << 4));
            *reinterpret_cast<short8*>(smem + off) = th;
            *reinterpret_cast<short8*>(smem + 8192 + off) = tl;
        }
        // ---- stage V^T per plane: VT[v][d 0..63][k 0..63] bf16, swizzled ----
        {
            const int d  = tid & 63;
            const int kg = tid >> 6;         // k-slot 0..7
            #pragma unroll
            for (int v = 0; v < 3; ++v) {
                const float* vp = Vb + (size_t)v * 32768 + (size_t)(k0 + kg * 8) * 64 + d;
                short8 t;
                #pragma unroll
                for (int j = 0; j < 8; ++j) t[j] = f2bf(vp[(size_t)j * 64]);
                *reinterpret_cast<short8*>(smem + 16384 + v * 8192 + d * 128 +
                                           ((kg * 16) ^ ((d & 7) << 4))) = t;
            }
        }
        __syncthreads();

        // ---- QK^T (4 key-tiles, split-bf16), softmax partial + dropout + P ----
        #pragma unroll
        for (int kt = 0; kt < 4; ++kt) {
            f32x4 acc = (f32x4){0.f, 0.f, 0.f, 0.f};
            #pragma unroll
            for (int u = 0; u < 2; ++u) {
                const int row = kt * 16 + lr;
                const int off = row * 128 + (((u * 32 + lg * 8) * 2) ^ ((row & 7) << 4));
                short8 khi = *reinterpret_cast<const short8*>(smem + off);
                short8 klo = *reinterpret_cast<const short8*>(smem + 8192 + off);
                acc = __builtin_amdgcn_mfma_f32_16x16x32_bf16(qlo[u], khi, acc, 0, 0, 0);
                acc = __builtin_amdgcn_mfma_f32_16x16x32_bf16(qhi[u], klo, acc, 0, 0, 0);
                acc = __builtin_amdgcn_mfma_f32_16x16x32_bf16(qhi[u], khi, acc, 0, 0, 0);
            }
            // C layout: lane holds C[q = lg*4+r][key = kt*16+lr]
            const int key = k0 + kt * 16 + lr;
            #pragma unroll
            for (int r = 0; r < 4; ++r) {
                const int qlocal = lg * 4 + r;
                float p = __expf(acc[r] * scale);
                lsum[r] += p;
                const uint32_t e =
                    (uint32_t)(bh * 512 + qt * 128 + w * 16 + qlocal) * 512u + (uint32_t)key;
                const uint32_t bits = threefry_bits(e);
                const float uu = __uint_as_float((bits >> 9) | 0x3F800000u) - 1.0f;
                const float pm = (uu < 0.65f) ? p : 0.0f;
                const int kl = kt * 16 + lr;
                *reinterpret_cast<short*>(Pw + qlocal * 128 +
                                          ((kl * 2) ^ ((qlocal & 7) << 4))) = f2bf(pm);
            }
        }
        // P is wave-local: no barrier needed before reading it back.

        // ---- PV: D[q][d] += P[q][k] * V[k][d] ----
        #pragma unroll
        for (int u = 0; u < 2; ++u) {
            short8 pf = *reinterpret_cast<const short8*>(
                Pw + lr * 128 + (((u * 32 + lg * 8) * 2) ^ ((lr & 7) << 4)));
            #pragma unroll
            for (int v = 0; v < 3; ++v) {
                #pragma unroll
                for (int nt = 0; nt < 4; ++nt) {
                    const int row = nt * 16 + lr;
                    short8 vf = *reinterpret_cast<const short8*>(
                        smem + 16384 + v * 8192 + row * 128 +
                        (((u * 32 + lg * 8) * 2) ^ ((row & 7) << 4)));
                    accO[v][nt] = __builtin_amdgcn_mfma_f32_16x16x32_bf16(
                        pf, vf, accO[v][nt], 0, 0, 0);
                }
            }
        }
        __syncthreads();   // all reads of K/VT done before next chunk's staging
    }

    // ---- denom reduce (within 16-lane group) and final scale+store ----
    #pragma unroll
    for (int r = 0; r < 4; ++r) {
        float s = lsum[r];
        s += __shfl_xor(s, 1); s += __shfl_xor(s, 2);
        s += __shfl_xor(s, 4); s += __shfl_xor(s, 8);
        lsum[r] = 1.0f / (s * 0.65f);
    }

    const int qbase = qt * 128 + w * 16 + lg * 4;
    #pragma unroll
    for (int v = 0; v < 3; ++v) {
        #pragma unroll
        for (int nt = 0; nt < 4; ++nt) {
            #pragma unroll
            for (int r = 0; r < 4; ++r) {
                const int q = qbase + r;
                const int d = nt * 16 + lr;
                out[(size_t)bh * 98304 + (size_t)v * 32768 + (size_t)q * 64 + d] =
                    accO[v][nt][r] * lsum[r];
            }
        }
    }
}

extern "C" void kernel_launch(void* const* d_in, const int* in_sizes, int n_in,
                              void* d_out, int out_size, void* d_ws, size_t ws_size,
                              hipStream_t stream) {
    const float* t0 = (const float*)d_in[0];
    const float* t1 = (const float*)d_in[1];
    const float* t2 = (const float*)d_in[2];
    const float* t3 = (const float*)d_in[3];
    float* out = (float*)d_out;

    // blockIdx = qt*128 + bh  =>  blockIdx%8 == bh%8: same-head q-tiles share an XCD
    attn_mfma_kernel<<<dim3(512), dim3(512), 0, stream>>>(t0, t1, t2, t3, out);
}